// Round 10
// baseline (143.166 us; speedup 1.0000x reference)
//
#include <hip/hip_runtime.h>
#include <hip/hip_fp16.h>
#include <math.h>

#define NB  4
#define DD  128
#define HH  128
#define WW  128
#define KS  11
#define PAD 5
#define NF  4             // fields: xbar, ybar, xybar, (x2+y2)bar
#define ZCK 16            // z outputs per K1 block (8 chunks -> 1024 blocks)
#define HCK 16            // h outputs per K2 block (8 chunks -> 1024 blocks)
#define RWI 140           // interleaved (x,y) slots per row: 6 pad + 128 + 6 pad

// Packed intermediate layout: A[n][z][h][q][f*2] fp16 (q = w-pair).
// One 16B vector holds all 4 fields for a w-pair -> 1 load/store per voxel-pair.
#define QS      8                 // halfs per q-slot (4 fields x 2 voxels)
#define HROW    (64 * QS)         // 512 halfs per h row
#define ZPLANE  (HH * HROW)       // 65536 halfs per z plane

using f32x2 = __attribute__((ext_vector_type(2))) float;

struct GW { float g[KS]; };

static __device__ __forceinline__ f32x2 vfma2(f32x2 a, f32x2 b, f32x2 c) {
    return __builtin_elementwise_fma(a, b, c);
}
static __device__ __forceinline__ unsigned h2u(__half2 v) {
    union { __half2 h; unsigned u; } x; x.h = v; return x.u;
}
static __device__ __forceinline__ f32x2 u2f2(unsigned u) {
    union { unsigned u; __half2 h; } x; x.u = u;
    const float2 f = __half22float2(x.h);
    return (f32x2){f.x, f.y};
}

// Wave-local LDS ordering fence: compile-time memory barrier + lgkm drain.
// Does NOT touch vmcnt (global prefetch stays in flight), does NOT sync waves.
#define WAVE_LDS_FENCE() asm volatile("s_waitcnt lgkmcnt(0)" ::: "memory")

// ---------------------------------------------------------------------------
// K1: fields + W-conv + D-conv fused, 2 w-voxels per thread. Barrier-free
// (wave owns its LDS row; WAVE_LDS_FENCE orders write->read per step).
// LDS row is (x,y)-INTERLEAVED: stage = 1 ds_write_b128, window = 7
// ds_read_b128 (8 LDS ops/step). W-conv packed over fields (xbar,ybar as one
// f32x2 chain; x^2+y^2 via packed squares + horizontal add). D-conv = packed
// shift-accumulator chains. 2-deep global prefetch, unroll-by-2.
// Block = 256 thr = 4 waves = 4 h-rows x 64 w-pairs; walks 16 z (+10 warm).
// ---------------------------------------------------------------------------
__global__ __launch_bounds__(256, 4)
void k1_wd(const float* __restrict__ img1, const float* __restrict__ img2,
           __half* __restrict__ A, GW gw) {
    __shared__ alignas(16) float srow[2][4][RWI][2];   // [buf][row][slot][xy]
    const int t  = threadIdx.x;
    const int b  = blockIdx.x;
    const int hb = b & 31;
    const int zc = (b >> 5) & 7;
    const int n  = b >> 8;
    const int r  = t >> 6;        // h-row == wave id
    const int q  = t & 63;        // w-pair == lane
    const int w0 = q * 2;
    const int h  = hb * 4 + r;
    const int z0 = zc * ZCK;

    // wave-local pad init: lanes 0..23 zero this wave's 2x12 pad slots
    if (q < 24) {
        const int buf = q / 12, i12 = q % 12;
        const int slot = (i12 < 6) ? i12 : (128 + i12);   // 0..5, 134..139
        srow[buf][r][slot][0] = 0.f;
        srow[buf][r][slot][1] = 0.f;
    }

    const long long inBase  = (long long)n * DD * HH * WW +
                              (long long)h * WW + w0;
    const long long outBase = (long long)n * DD * ZPLANE +
                              (long long)h * HROW + (long long)q * QS;

    // D-chains: packed over fields. A = (xbar, ybar), B = (xybar, ssbar),
    // suffix 0/1 = voxel. 4 chains x 11 x f32x2.
    f32x2 cA0[KS], cA1[KS], cB0[KS], cB1[KS];
    #pragma unroll
    for (int j = 0; j < KS; ++j) {
        cA0[j] = (f32x2){0.f, 0.f}; cA1[j] = (f32x2){0.f, 0.f};
        cB0[j] = (f32x2){0.f, 0.f}; cB1[j] = (f32x2){0.f, 0.f};
    }

    const int STEPS = ZCK + 2 * PAD;   // 26

    float2 rx0 = make_float2(0.f, 0.f), ry0 = rx0, rx1 = rx0, ry1 = rx0;
    {
        const int zi0 = z0 - PAD;
        if (zi0 >= 0) {
            const long long off = inBase + (long long)zi0 * (HH * WW);
            rx0 = *(const float2*)(img1 + off);
            ry0 = *(const float2*)(img2 + off);
        }
        const int zi1 = z0 - PAD + 1;
        if (zi1 >= 0) {
            const long long off = inBase + (long long)zi1 * (HH * WW);
            rx1 = *(const float2*)(img1 + off);
            ry1 = *(const float2*)(img2 + off);
        }
    }
    {   // stage plane 0 into buf 0: slots w0+6, w0+7 (byte 16q+48, 16B aligned)
        float4 st; st.x = rx0.x; st.y = ry0.x; st.z = rx0.y; st.w = ry0.y;
        *(float4*)&srow[0][r][w0 + 6][0] = st;
    }

    #define DCHAIN(ACC, V)                                                     \
        _Pragma("unroll")                                                      \
        for (int j = KS - 1; j >= 1; --j) {                                    \
            const f32x2 gg = {gw.g[j], gw.g[j]};                               \
            ACC[j] = vfma2(gg, V, ACC[j - 1]);                                 \
        }                                                                      \
        { const f32x2 g0 = {gw.g[0], gw.g[0]}; ACC[0] = g0 * (V); }

    #define K1_STEP(S, CUR, NXT, RXC, RYC, RXN, RYN, DOST)                     \
    {                                                                          \
        /* order previous step's ds_write before this step's ds_reads */       \
        WAVE_LDS_FENCE();                                                      \
        {   /* issue load of plane S+2 into the regs freed last step */        \
            const int zi = z0 - PAD + (S) + 2;                                 \
            float2 lx = make_float2(0.f, 0.f), ly = lx;                        \
            if ((S) + 2 < STEPS && zi >= 0 && zi < DD) {                       \
                const long long off = inBase + (long long)zi * (HH * WW);      \
                lx = *(const float2*)(img1 + off);                             \
                ly = *(const float2*)(img2 + off);                             \
            }                                                                  \
            RXC = lx; RYC = ly;                                                \
        }                                                                      \
        /* window: 7 ds_read_b128 of interleaved (x,y) pairs, e = 0..13 */     \
        f32x2 pair_[14]; f32x2 qsq_[14]; float pxy_[14];                       \
        _Pragma("unroll")                                                      \
        for (int i = 0; i < 7; ++i) {                                          \
            const float4 v = *(const float4*)&srow[CUR][r][w0 + 2 * i][0];     \
            pair_[2*i]   = (f32x2){v.x, v.y};                                  \
            pair_[2*i+1] = (f32x2){v.z, v.w};                                  \
            qsq_[2*i]    = pair_[2*i] * pair_[2*i];                            \
            qsq_[2*i+1]  = pair_[2*i+1] * pair_[2*i+1];                        \
            pxy_[2*i]    = v.x * v.y;                                          \
            pxy_[2*i+1]  = v.z * v.w;                                          \
        }                                                                      \
        /* W-conv: vox0 uses e=k+1, vox1 e=k+2 */                              \
        f32x2 c01_0 = {0.f, 0.f}, c01_1 = {0.f, 0.f};                          \
        f32x2 cQ_0  = {0.f, 0.f}, cQ_1  = {0.f, 0.f};                          \
        float c2_0 = 0.f, c2_1 = 0.f;                                          \
        _Pragma("unroll")                                                      \
        for (int k = 0; k < KS; ++k) {                                         \
            const float g = gw.g[k];                                           \
            const f32x2 gg = {g, g};                                           \
            c01_0 = vfma2(gg, pair_[k + 1], c01_0);                            \
            c01_1 = vfma2(gg, pair_[k + 2], c01_1);                            \
            cQ_0  = vfma2(gg, qsq_[k + 1], cQ_0);                              \
            cQ_1  = vfma2(gg, qsq_[k + 2], cQ_1);                              \
            c2_0  = fmaf(g, pxy_[k + 1], c2_0);                                \
            c2_1  = fmaf(g, pxy_[k + 2], c2_1);                                \
        }                                                                      \
        /* stage plane S+1 into buf NXT (wave-local; fenced next step) */      \
        {                                                                      \
            float4 st; st.x = RXN.x; st.y = RYN.x; st.z = RXN.y; st.w = RYN.y; \
            *(float4*)&srow[NXT][r][w0 + 6][0] = st;                           \
        }                                                                      \
        /* packed D-conv chains */                                             \
        const f32x2 vB0 = {c2_0, cQ_0.x + cQ_0.y};                             \
        const f32x2 vB1 = {c2_1, cQ_1.x + cQ_1.y};                             \
        DCHAIN(cA0, c01_0)                                                     \
        DCHAIN(cA1, c01_1)                                                     \
        DCHAIN(cB0, vB0)                                                       \
        DCHAIN(cB1, vB1)                                                       \
        if (DOST) {                                                            \
            const int zo = z0 + (S) - 2 * PAD;                                 \
            uint4 pk;                                                          \
            pk.x = h2u(__float22half2_rn(                                      \
                       make_float2(cA0[KS-1].x, cA1[KS-1].x)));  /* xbar  */   \
            pk.y = h2u(__float22half2_rn(                                      \
                       make_float2(cA0[KS-1].y, cA1[KS-1].y)));  /* ybar  */   \
            pk.z = h2u(__float22half2_rn(                                      \
                       make_float2(cB0[KS-1].x, cB1[KS-1].x)));  /* xybar */   \
            pk.w = h2u(__float22half2_rn(                                      \
                       make_float2(cB0[KS-1].y, cB1[KS-1].y)));  /* ssbar */   \
            *(uint4*)(A + outBase + (long long)zo * ZPLANE) = pk;              \
        }                                                                      \
    }

    for (int s2 = 0; s2 < 2 * PAD; s2 += 2) {          // warmup, no store
        K1_STEP(s2,     0, 1, rx0, ry0, rx1, ry1, 0)
        K1_STEP(s2 + 1, 1, 0, rx1, ry1, rx0, ry0, 0)
    }
    for (int s2 = 2 * PAD; s2 < STEPS; s2 += 2) {      // main, store
        K1_STEP(s2,     0, 1, rx0, ry0, rx1, ry1, 1)
        K1_STEP(s2 + 1, 1, 0, rx1, ry1, rx0, ry0, 1)
    }
    #undef K1_STEP
    #undef DCHAIN
}

// ---------------------------------------------------------------------------
// K2: H-conv (packed f32x2 shift chains) + packed SSIM + block reduction.
// 2 w-voxels per thread; ONE dwordx4 load per step delivers all 4 fields;
// 2-deep prefetch; rcp+NR division. No LDS staging (A is L2/L3-resident).
// Block = 256 thr = 4 z-rows x 64 w-pairs, walks h over 16 rows (+10 warm).
// ---------------------------------------------------------------------------
__global__ __launch_bounds__(256, 4)
void k2_hssim(const __half* __restrict__ A, double* __restrict__ partials,
              GW gw) {
    const int t  = threadIdx.x;
    const int b  = blockIdx.x;
    const int hc = b & 7;
    const int zp = (b >> 3) & 31;
    const int n  = b >> 8;
    const int zl = t >> 6;
    const int q  = t & 63;
    const int z  = zp * 4 + zl;
    const int h0 = hc * HCK;

    const long long colBase =
        ((long long)(n * DD + z)) * ZPLANE + (long long)q * QS;

    f32x2 acc[NF][KS];
    #pragma unroll
    for (int f = 0; f < NF; ++f)
        #pragma unroll
        for (int j = 0; j < KS; ++j) acc[f][j] = (f32x2){0.f, 0.f};

    const int STEPS = HCK + 2 * PAD;   // 26

    uint4 pfA = make_uint4(0u, 0u, 0u, 0u), pfB = pfA;
    {
        const int hi0 = h0 - PAD;
        if (hi0 >= 0)
            pfA = *(const uint4*)(A + colBase + (long long)hi0 * HROW);
        const int hi1 = h0 - PAD + 1;
        if (hi1 >= 0)
            pfB = *(const uint4*)(A + colBase + (long long)hi1 * HROW);
    }

    const f32x2 C1v = {1e-4f, 1e-4f}, C2v = {9e-4f, 9e-4f};
    const f32x2 TWO = {2.f, 2.f};
    f32x2 sum = {0.f, 0.f};

    #define K2_STEP(S, PFC, DOSSIM)                                            \
    {                                                                          \
        f32x2 v[NF];                                                           \
        v[0] = u2f2(PFC.x); v[1] = u2f2(PFC.y);                                \
        v[2] = u2f2(PFC.z); v[3] = u2f2(PFC.w);                                \
        {   /* prefetch row S+2 */                                             \
            const int hi = h0 - PAD + (S) + 2;                                 \
            uint4 nv = make_uint4(0u, 0u, 0u, 0u);                             \
            if ((S) + 2 < STEPS && hi >= 0 && hi < HH)                         \
                nv = *(const uint4*)(A + colBase + (long long)hi * HROW);      \
            PFC = nv;                                                          \
        }                                                                      \
        _Pragma("unroll")                                                      \
        for (int f = 0; f < NF; ++f) {                                         \
            _Pragma("unroll")                                                  \
            for (int j = KS - 1; j >= 1; --j) {                                \
                const f32x2 gg = {gw.g[j], gw.g[j]};                           \
                acc[f][j] = vfma2(gg, v[f], acc[f][j - 1]);                    \
            }                                                                  \
            const f32x2 g0 = {gw.g[0], gw.g[0]};                               \
            acc[f][0] = g0 * v[f];                                             \
        }                                                                      \
        if (DOSSIM) {                                                          \
            const f32x2 mu1 = acc[0][KS - 1], mu2 = acc[1][KS - 1];            \
            const f32x2 mu1s = mu1 * mu1, mu2s = mu2 * mu2, mu12 = mu1 * mu2;  \
            const f32x2 sg12 = acc[2][KS - 1] - mu12;                          \
            const f32x2 sgss = acc[3][KS - 1] - mu1s - mu2s;                   \
            const f32x2 num = vfma2(TWO, mu12, C1v) * vfma2(TWO, sg12, C2v);   \
            const f32x2 den = (mu1s + mu2s + C1v) * (sgss + C2v);              \
            f32x2 rr;                                                          \
            rr.x = __builtin_amdgcn_rcpf(den.x);                               \
            rr.y = __builtin_amdgcn_rcpf(den.y);                               \
            rr = rr * vfma2(-den, rr, TWO);   /* 1 NR step */                  \
            sum = vfma2(num, rr, sum);                                         \
        }                                                                      \
    }

    for (int s2 = 0; s2 < 2 * PAD; s2 += 2) {
        K2_STEP(s2,     pfA, 0)
        K2_STEP(s2 + 1, pfB, 0)
    }
    for (int s2 = 2 * PAD; s2 < STEPS; s2 += 2) {
        K2_STEP(s2,     pfA, 1)
        K2_STEP(s2 + 1, pfB, 1)
    }
    #undef K2_STEP

    __shared__ double red[256];
    red[t] = (double)sum.x + (double)sum.y;
    __syncthreads();
    for (int sft = 128; sft > 0; sft >>= 1) {
        if (t < sft) red[t] += red[t + sft];
        __syncthreads();
    }
    if (t == 0) partials[b] = red[0];
}

// ---------------------------------------------------------------------------
__global__ __launch_bounds__(256)
void k4_reduce(const double* __restrict__ partials, int nPart,
               float* __restrict__ out) {
    __shared__ double red[256];
    const int t = threadIdx.x;
    double s = 0.0;
    for (int i = t; i < nPart; i += 256) s += partials[i];
    red[t] = s;
    __syncthreads();
    for (int sft = 128; sft > 0; sft >>= 1) {
        if (t < sft) red[t] += red[t + sft];
        __syncthreads();
    }
    if (t == 0) out[0] = (float)(red[0] / (double)((long long)NB * DD * HH * WW));
}

// ---------------------------------------------------------------------------
extern "C" void kernel_launch(void* const* d_in, const int* in_sizes, int n_in,
                              void* d_out, int out_size, void* d_ws, size_t ws_size,
                              hipStream_t stream) {
    const float* img1 = (const float*)d_in[0];
    const float* img2 = (const float*)d_in[1];
    float* out = (float*)d_out;

    GW gw;
    {
        double gs[KS], ssum = 0.0;
        for (int i = 0; i < KS; ++i) {
            const double c = (double)(i - KS / 2);
            gs[i] = exp(-c * c / (2.0 * 1.5 * 1.5));
            ssum += gs[i];
        }
        for (int i = 0; i < KS; ++i) gw.g[i] = (float)(gs[i] / ssum);
    }

    __half* A = (__half*)d_ws;   // [n][z][h][q][f*2] fp16, 67 MB
    double* partials =
        (double*)((char*)d_ws + (long long)NB * DD * ZPLANE * sizeof(__half));

    const int nBlocksK1 = NB * 32 * (DD / ZCK);   // 1024
    const int nBlocksK2 = NB * 32 * (HH / HCK);   // 1024

    k1_wd<<<nBlocksK1, 256, 0, stream>>>(img1, img2, A, gw);
    k2_hssim<<<nBlocksK2, 256, 0, stream>>>(A, partials, gw);
    k4_reduce<<<1, 256, 0, stream>>>(partials, nBlocksK2, out);
}

// Round 11
// 66.295 us; speedup vs baseline: 2.1595x; 2.1595x over previous
//
#include <hip/hip_runtime.h>
#include <hip/hip_fp16.h>
#include <math.h>

#define NB  4
#define DD  128
#define HH  128
#define WW  128
#define KS  11
#define PAD 5
#define NF  4             // fields: xbar, ybar, xybar, (x2+y2)bar
#define ZCK 16            // z outputs per K1 block (8 chunks -> 1024 blocks)
#define HCK 16            // h outputs per K2 block (8 chunks -> 1024 blocks)
#define RW  144           // padded LDS row length (floats)
#define LOFF 6            // w-coord u lives at LDS slot LOFF+u

// Packed intermediate layout: A[n][z][h][q][f*2] fp16 (q = w-pair).
// One 16B vector holds all 4 fields for a w-pair -> 1 load/store per voxel-pair.
#define QS      8                 // halfs per q-slot (4 fields x 2 voxels)
#define HROW    (64 * QS)         // 512 halfs per h row
#define ZPLANE  (HH * HROW)       // 65536 halfs per z plane

using f32x2 = __attribute__((ext_vector_type(2))) float;

struct GW { float g[KS]; };

static __device__ __forceinline__ f32x2 vfma2(f32x2 a, f32x2 b, f32x2 c) {
    return __builtin_elementwise_fma(a, b, c);
}
static __device__ __forceinline__ unsigned h2u(__half2 v) {
    union { __half2 h; unsigned u; } x; x.h = v; return x.u;
}
static __device__ __forceinline__ f32x2 u2f2(unsigned u) {
    union { unsigned u; __half2 h; } x; x.u = u;
    const float2 f = __half22float2(x.h);
    return (f32x2){f.x, f.y};
}

// Wave-local LDS ordering fence: compile-time memory barrier + lgkm drain.
// Does NOT touch vmcnt (global prefetch stays in flight), does NOT sync waves.
#define WAVE_LDS_FENCE() asm volatile("s_waitcnt lgkmcnt(0)" ::: "memory")

// ---------------------------------------------------------------------------
// K1: fields + W-conv + D-conv fused, 2 w-voxels per thread. BARRIER-FREE:
// each wave owns one h-row and touches only its own LDS slice; cross-lane
// write->read ordering enforced by WAVE_LDS_FENCE() per step. Ping-pong LDS
// rows, 2-deep float2 prefetch, unroll-by-2, packed f32x2 D-chains, single
// dwordx4 store per step. NO VGPR cap (R10 lesson: (256,4) caused spills).
// Block = 256 thr = 4 waves = 4 h-rows x 64 w-pairs; walks 16 z (+10 warm).
// ---------------------------------------------------------------------------
__global__ __launch_bounds__(256)
void k1_wd(const float* __restrict__ img1, const float* __restrict__ img2,
           __half* __restrict__ A, GW gw) {
    __shared__ alignas(16) float srow[2][2][4][RW];   // [buf][img][row][slot]
    const int t  = threadIdx.x;
    const int b  = blockIdx.x;
    const int hb = b & 31;
    const int zc = (b >> 5) & 7;
    const int n  = b >> 8;
    const int r  = t >> 6;        // h-row == wave id
    const int q  = t & 63;        // w-pair == lane
    const int w0 = q * 2;
    const int h  = hb * 4 + r;
    const int z0 = zc * ZCK;

    // wave-local pad init: lanes 0..47 zero this wave's 2x2x12 pad slots
    if (q < 48) {
        const int grp = q / 12, s12 = q % 12;      // grp = [buf][img]
        const int slot = (s12 < 6) ? s12 : (128 + s12);
        srow[grp >> 1][grp & 1][r][slot] = 0.f;
    }

    const long long inBase  = (long long)n * DD * HH * WW +
                              (long long)h * WW + w0;
    const long long outBase = (long long)n * DD * ZPLANE +
                              (long long)h * HROW + (long long)q * QS;

    f32x2 acc[NF][KS];
    #pragma unroll
    for (int f = 0; f < NF; ++f)
        #pragma unroll
        for (int j = 0; j < KS; ++j) acc[f][j] = (f32x2){0.f, 0.f};

    const int STEPS = ZCK + 2 * PAD;   // 26

    float2 rx0 = make_float2(0.f, 0.f), ry0 = rx0, rx1 = rx0, ry1 = rx0;
    {
        const int zi0 = z0 - PAD;
        if (zi0 >= 0) {
            const long long off = inBase + (long long)zi0 * (HH * WW);
            rx0 = *(const float2*)(img1 + off);
            ry0 = *(const float2*)(img2 + off);
        }
        const int zi1 = z0 - PAD + 1;
        if (zi1 >= 0) {
            const long long off = inBase + (long long)zi1 * (HH * WW);
            rx1 = *(const float2*)(img1 + off);
            ry1 = *(const float2*)(img2 + off);
        }
    }
    *(float2*)&srow[0][0][r][LOFF + w0] = rx0;
    *(float2*)&srow[0][1][r][LOFF + w0] = ry0;
    // no block barrier: wave-local data only; fence at top of each step

    // element e (0..13) = w-coord w0-6+e = slot w0+e
    #define ELV(A2, i) ((i) & 1 ? A2[(i) >> 1].y : A2[(i) >> 1].x)

    #define K1_STEP(S, CUR, NXT, RXC, RYC, RXN, RYN, DOST)                     \
    {                                                                          \
        /* order previous step's ds_writes before this step's ds_reads */      \
        WAVE_LDS_FENCE();                                                      \
        {   /* issue load of plane S+2 into the regs freed last step */        \
            const int zi = z0 - PAD + (S) + 2;                                 \
            float2 lx = make_float2(0.f, 0.f), ly = lx;                        \
            if ((S) + 2 < STEPS && zi >= 0 && zi < DD) {                       \
                const long long off = inBase + (long long)zi * (HH * WW);      \
                lx = *(const float2*)(img1 + off);                             \
                ly = *(const float2*)(img2 + off);                             \
            }                                                                  \
            RXC = lx; RYC = ly;                                                \
        }                                                                      \
        /* load 14 values per image from buf CUR (7 x ds_read_b64 each) */     \
        f32x2 xv2[7], yv2[7];                                                  \
        _Pragma("unroll")                                                      \
        for (int i = 0; i < 7; ++i) {                                          \
            const float2 ax = *(const float2*)&srow[CUR][0][r][w0 + 2 * i];    \
            const float2 ay = *(const float2*)&srow[CUR][1][r][w0 + 2 * i];    \
            xv2[i] = (f32x2){ax.x, ax.y};                                      \
            yv2[i] = (f32x2){ay.x, ay.y};                                      \
        }                                                                      \
        /* packed products shared by both voxels */                            \
        f32x2 pv2[7], qv2[7];                                                  \
        _Pragma("unroll")                                                      \
        for (int i = 0; i < 7; ++i) {                                          \
            pv2[i] = xv2[i] * yv2[i];                                          \
            qv2[i] = vfma2(yv2[i], yv2[i], xv2[i] * xv2[i]);                   \
        }                                                                      \
        /* W-conv: vox0 uses elements k+1, vox1 uses k+2 */                    \
        float a0x = 0.f, a0y = 0.f, a1x = 0.f, a1y = 0.f;                      \
        float a2x = 0.f, a2y = 0.f, a3x = 0.f, a3y = 0.f;                      \
        _Pragma("unroll")                                                      \
        for (int k = 0; k < KS; ++k) {                                         \
            const float g = gw.g[k];                                           \
            a0x = fmaf(g, ELV(xv2, k + 1), a0x);                               \
            a0y = fmaf(g, ELV(xv2, k + 2), a0y);                               \
            a1x = fmaf(g, ELV(yv2, k + 1), a1x);                               \
            a1y = fmaf(g, ELV(yv2, k + 2), a1y);                               \
            a2x = fmaf(g, ELV(pv2, k + 1), a2x);                               \
            a2y = fmaf(g, ELV(pv2, k + 2), a2y);                               \
            a3x = fmaf(g, ELV(qv2, k + 1), a3x);                               \
            a3y = fmaf(g, ELV(qv2, k + 2), a3y);                               \
        }                                                                      \
        /* stage plane S+1 into buf NXT (wave-local; fenced next step) */      \
        *(float2*)&srow[NXT][0][r][LOFF + w0] = RXN;                           \
        *(float2*)&srow[NXT][1][r][LOFF + w0] = RYN;                           \
        /* packed D-conv shift-accumulator chains */                           \
        f32x2 v[NF];                                                           \
        v[0] = (f32x2){a0x, a0y}; v[1] = (f32x2){a1x, a1y};                    \
        v[2] = (f32x2){a2x, a2y}; v[3] = (f32x2){a3x, a3y};                    \
        _Pragma("unroll")                                                      \
        for (int f = 0; f < NF; ++f) {                                         \
            _Pragma("unroll")                                                  \
            for (int j = KS - 1; j >= 1; --j) {                                \
                const f32x2 gg = {gw.g[j], gw.g[j]};                           \
                acc[f][j] = vfma2(gg, v[f], acc[f][j - 1]);                    \
            }                                                                  \
            const f32x2 g0 = {gw.g[0], gw.g[0]};                               \
            acc[f][0] = g0 * v[f];                                             \
        }                                                                      \
        if (DOST) {                                                            \
            const int zo = z0 + (S) - 2 * PAD;                                 \
            uint4 pk;                                                          \
            pk.x = h2u(__float22half2_rn(                                      \
                       make_float2(acc[0][KS-1].x, acc[0][KS-1].y)));          \
            pk.y = h2u(__float22half2_rn(                                      \
                       make_float2(acc[1][KS-1].x, acc[1][KS-1].y)));          \
            pk.z = h2u(__float22half2_rn(                                      \
                       make_float2(acc[2][KS-1].x, acc[2][KS-1].y)));          \
            pk.w = h2u(__float22half2_rn(                                      \
                       make_float2(acc[3][KS-1].x, acc[3][KS-1].y)));          \
            *(uint4*)(A + outBase + (long long)zo * ZPLANE) = pk;              \
        }                                                                      \
    }

    for (int s2 = 0; s2 < 2 * PAD; s2 += 2) {          // warmup, no store
        K1_STEP(s2,     0, 1, rx0, ry0, rx1, ry1, 0)
        K1_STEP(s2 + 1, 1, 0, rx1, ry1, rx0, ry0, 0)
    }
    for (int s2 = 2 * PAD; s2 < STEPS; s2 += 2) {      // main, store
        K1_STEP(s2,     0, 1, rx0, ry0, rx1, ry1, 1)
        K1_STEP(s2 + 1, 1, 0, rx1, ry1, rx0, ry0, 1)
    }
    #undef K1_STEP
    #undef ELV
}

// ---------------------------------------------------------------------------
// K2: H-conv (packed f32x2 shift chains) + packed SSIM + block reduction.
// 2 w-voxels per thread; ONE dwordx4 load per step delivers all 4 fields;
// 2-deep prefetch; rcp+NR division. No LDS staging (A is L2/L3-resident).
// Block = 256 thr = 4 z-rows x 64 w-pairs, walks h over 16 rows (+10 warm).
// ---------------------------------------------------------------------------
__global__ __launch_bounds__(256)
void k2_hssim(const __half* __restrict__ A, double* __restrict__ partials,
              GW gw) {
    const int t  = threadIdx.x;
    const int b  = blockIdx.x;
    const int hc = b & 7;
    const int zp = (b >> 3) & 31;
    const int n  = b >> 8;
    const int zl = t >> 6;
    const int q  = t & 63;
    const int z  = zp * 4 + zl;
    const int h0 = hc * HCK;

    const long long colBase =
        ((long long)(n * DD + z)) * ZPLANE + (long long)q * QS;

    f32x2 acc[NF][KS];
    #pragma unroll
    for (int f = 0; f < NF; ++f)
        #pragma unroll
        for (int j = 0; j < KS; ++j) acc[f][j] = (f32x2){0.f, 0.f};

    const int STEPS = HCK + 2 * PAD;   // 26

    uint4 pfA = make_uint4(0u, 0u, 0u, 0u), pfB = pfA;
    {
        const int hi0 = h0 - PAD;
        if (hi0 >= 0)
            pfA = *(const uint4*)(A + colBase + (long long)hi0 * HROW);
        const int hi1 = h0 - PAD + 1;
        if (hi1 >= 0)
            pfB = *(const uint4*)(A + colBase + (long long)hi1 * HROW);
    }

    const f32x2 C1v = {1e-4f, 1e-4f}, C2v = {9e-4f, 9e-4f};
    const f32x2 TWO = {2.f, 2.f};
    f32x2 sum = {0.f, 0.f};

    #define K2_STEP(S, PFC, DOSSIM)                                            \
    {                                                                          \
        f32x2 v[NF];                                                           \
        v[0] = u2f2(PFC.x); v[1] = u2f2(PFC.y);                                \
        v[2] = u2f2(PFC.z); v[3] = u2f2(PFC.w);                                \
        {   /* prefetch row S+2 */                                             \
            const int hi = h0 - PAD + (S) + 2;                                 \
            uint4 nv = make_uint4(0u, 0u, 0u, 0u);                             \
            if ((S) + 2 < STEPS && hi >= 0 && hi < HH)                         \
                nv = *(const uint4*)(A + colBase + (long long)hi * HROW);      \
            PFC = nv;                                                          \
        }                                                                      \
        _Pragma("unroll")                                                      \
        for (int f = 0; f < NF; ++f) {                                         \
            _Pragma("unroll")                                                  \
            for (int j = KS - 1; j >= 1; --j) {                                \
                const f32x2 gg = {gw.g[j], gw.g[j]};                           \
                acc[f][j] = vfma2(gg, v[f], acc[f][j - 1]);                    \
            }                                                                  \
            const f32x2 g0 = {gw.g[0], gw.g[0]};                               \
            acc[f][0] = g0 * v[f];                                             \
        }                                                                      \
        if (DOSSIM) {                                                          \
            const f32x2 mu1 = acc[0][KS - 1], mu2 = acc[1][KS - 1];            \
            const f32x2 mu1s = mu1 * mu1, mu2s = mu2 * mu2, mu12 = mu1 * mu2;  \
            const f32x2 sg12 = acc[2][KS - 1] - mu12;                          \
            const f32x2 sgss = acc[3][KS - 1] - mu1s - mu2s;                   \
            const f32x2 num = vfma2(TWO, mu12, C1v) * vfma2(TWO, sg12, C2v);   \
            const f32x2 den = (mu1s + mu2s + C1v) * (sgss + C2v);              \
            f32x2 rr;                                                          \
            rr.x = __builtin_amdgcn_rcpf(den.x);                               \
            rr.y = __builtin_amdgcn_rcpf(den.y);                               \
            rr = rr * vfma2(-den, rr, TWO);   /* 1 NR step */                  \
            sum = vfma2(num, rr, sum);                                         \
        }                                                                      \
    }

    for (int s2 = 0; s2 < 2 * PAD; s2 += 2) {
        K2_STEP(s2,     pfA, 0)
        K2_STEP(s2 + 1, pfB, 0)
    }
    for (int s2 = 2 * PAD; s2 < STEPS; s2 += 2) {
        K2_STEP(s2,     pfA, 1)
        K2_STEP(s2 + 1, pfB, 1)
    }
    #undef K2_STEP

    __shared__ double red[256];
    red[t] = (double)sum.x + (double)sum.y;
    __syncthreads();
    for (int sft = 128; sft > 0; sft >>= 1) {
        if (t < sft) red[t] += red[t + sft];
        __syncthreads();
    }
    if (t == 0) partials[b] = red[0];
}

// ---------------------------------------------------------------------------
__global__ __launch_bounds__(256)
void k4_reduce(const double* __restrict__ partials, int nPart,
               float* __restrict__ out) {
    __shared__ double red[256];
    const int t = threadIdx.x;
    double s = 0.0;
    for (int i = t; i < nPart; i += 256) s += partials[i];
    red[t] = s;
    __syncthreads();
    for (int sft = 128; sft > 0; sft >>= 1) {
        if (t < sft) red[t] += red[t + sft];
        __syncthreads();
    }
    if (t == 0) out[0] = (float)(red[0] / (double)((long long)NB * DD * HH * WW));
}

// ---------------------------------------------------------------------------
extern "C" void kernel_launch(void* const* d_in, const int* in_sizes, int n_in,
                              void* d_out, int out_size, void* d_ws, size_t ws_size,
                              hipStream_t stream) {
    const float* img1 = (const float*)d_in[0];
    const float* img2 = (const float*)d_in[1];
    float* out = (float*)d_out;

    GW gw;
    {
        double gs[KS], ssum = 0.0;
        for (int i = 0; i < KS; ++i) {
            const double c = (double)(i - KS / 2);
            gs[i] = exp(-c * c / (2.0 * 1.5 * 1.5));
            ssum += gs[i];
        }
        for (int i = 0; i < KS; ++i) gw.g[i] = (float)(gs[i] / ssum);
    }

    __half* A = (__half*)d_ws;   // [n][z][h][q][f*2] fp16, 67 MB
    double* partials =
        (double*)((char*)d_ws + (long long)NB * DD * ZPLANE * sizeof(__half));

    const int nBlocksK1 = NB * 32 * (DD / ZCK);   // 1024
    const int nBlocksK2 = NB * 32 * (HH / HCK);   // 1024

    k1_wd<<<nBlocksK1, 256, 0, stream>>>(img1, img2, A, gw);
    k2_hssim<<<nBlocksK2, 256, 0, stream>>>(A, partials, gw);
    k4_reduce<<<1, 256, 0, stream>>>(partials, nBlocksK2, out);
}